// Round 3
// baseline (575.796 us; speedup 1.0000x reference)
//
#include <hip/hip_runtime.h>

// 3-layer GCN (PyG GCNConv semantics): deg/norm build -> CSR by dst ->
// per layer: GEMM (N x 128 @ 128 x 128) then CSR aggregation + bias (+relu),
// final 128->16 linear fused into the last aggregation. All fp32.
//
// R3: GEMM reads the A-tile as wave-uniform global float4 (scalar-pipe
// s_load, SGPR operand into v_fma) instead of staging in LDS — the LDS
// round-trip (1 MB of ds_read per 8 KB tile) was the GEMM bottleneck.
// Aggregation batches 16 gathers in flight per thread (mean degree 12 ->
// one burst covers most nodes).

#define FD 128
#define NCLS 16

__global__ __launch_bounds__(256) void k_init_deg(int* __restrict__ degi, int n) {
  int i = blockIdx.x * 256 + threadIdx.x;
  if (i < n) degi[i] = 1;  // self-loop
}

__global__ __launch_bounds__(256) void k_count(const int* __restrict__ dst,
                                               int* __restrict__ degi, int e) {
  int i = blockIdx.x * 256 + threadIdx.x;
  if (i < e) atomicAdd(&degi[dst[i]], 1);
}

__global__ __launch_bounds__(256) void k_dis(const int* __restrict__ degi,
                                             float* __restrict__ dis, int n) {
  int i = blockIdx.x * 256 + threadIdx.x;
  if (i < n) dis[i] = rsqrtf((float)degi[i]);
}

// Phase A: per-1024-chunk exclusive scan of (deg-1) = in-edge count
__global__ __launch_bounds__(1024) void k_scanA(const int* __restrict__ degi,
                                                int* __restrict__ ptr,
                                                int* __restrict__ bsum, int n) {
  __shared__ int buf[1024];
  int tid = threadIdx.x;
  int i = blockIdx.x * 1024 + tid;
  int v = (i < n) ? (degi[i] - 1) : 0;
  buf[tid] = v;
  __syncthreads();
  for (int off = 1; off < 1024; off <<= 1) {
    int t = (tid >= off) ? buf[tid - off] : 0;
    __syncthreads();
    buf[tid] += t;
    __syncthreads();
  }
  if (i < n) ptr[i] = buf[tid] - v;  // local exclusive
  if (tid == 1023) bsum[blockIdx.x] = buf[1023];
}

// Phase B: tiny serial scan of ~49 block sums
__global__ void k_scanB(int* __restrict__ bsum, int nb) {
  if (threadIdx.x == 0 && blockIdx.x == 0) {
    int run = 0;
    for (int b = 0; b < nb; ++b) { int t = bsum[b]; bsum[b] = run; run += t; }
  }
}

// Phase C: add chunk offsets, init fill cursors, write ptr[n]
__global__ __launch_bounds__(256) void k_scanC(int* __restrict__ ptr,
                                               int* __restrict__ cur,
                                               const int* __restrict__ bsum,
                                               int n, int e) {
  int i = blockIdx.x * 256 + threadIdx.x;
  if (i < n) {
    int p = ptr[i] + bsum[i >> 10];
    ptr[i] = p;
    cur[i] = p;
  }
  if (i == 0) ptr[n] = e;
}

__global__ __launch_bounds__(256) void k_fill(const int* __restrict__ src,
                                              const int* __restrict__ dst,
                                              int* __restrict__ cur,
                                              const float* __restrict__ dis,
                                              int2* __restrict__ sn, int e) {
  int i = blockIdx.x * 256 + threadIdx.x;
  if (i < e) {
    int s = src[i], d = dst[i];
    int p = atomicAdd(&cur[d], 1);
    sn[p] = make_int2(s, __float_as_int(dis[s] * dis[d]));
  }
}

// out[rbase..rbase+15][:] = in rows @ W (128x128). blockDim=128, 16 rows/block.
// A-tile addresses are functions of blockIdx only -> wave-uniform -> scalar
// loads; W column loads are lane-coalesced (256 B / wave / instr).
__global__ __launch_bounds__(128) void k_gemm128(const float* __restrict__ in,
                                                 const float* __restrict__ W,
                                                 float* __restrict__ out) {
  int tid = threadIdx.x;
  int rbase = blockIdx.x * 16;
  float acc[16];
#pragma unroll
  for (int r = 0; r < 16; ++r) acc[r] = 0.f;
  for (int k = 0; k < FD; k += 4) {
    float w0 = W[(k + 0) * FD + tid];
    float w1 = W[(k + 1) * FD + tid];
    float w2 = W[(k + 2) * FD + tid];
    float w3 = W[(k + 3) * FD + tid];
#pragma unroll
    for (int r = 0; r < 16; ++r) {
      float4 a = *reinterpret_cast<const float4*>(&in[(rbase + r) * FD + k]);
      acc[r] = fmaf(a.x, w0, acc[r]);
      acc[r] = fmaf(a.y, w1, acc[r]);
      acc[r] = fmaf(a.z, w2, acc[r]);
      acc[r] = fmaf(a.w, w3, acc[r]);
    }
  }
#pragma unroll
  for (int r = 0; r < 16; ++r)
    out[(rbase + r) * FD + tid] = acc[r];
}

// Batched CSR aggregation: 16 independent gathers in flight per thread.
// Short batches padded with (node, w=0); self row is cache-hot so the
// padded gathers are near-free.
__device__ __forceinline__ float agg_acc(const float* __restrict__ t,
                                         const int* __restrict__ ptr,
                                         const int2* __restrict__ sn,
                                         const float* __restrict__ dis,
                                         int node, int f) {
  float d = dis[node];
  float acc = t[node * FD + f] * (d * d);
  int e0 = ptr[node], e1 = ptr[node + 1];
  for (int e = e0; e < e1; e += 16) {
    int s[16];
    float w[16];
#pragma unroll
    for (int j = 0; j < 16; ++j) {
      if (e + j < e1) {
        int2 p = sn[e + j];
        s[j] = p.x;
        w[j] = __int_as_float(p.y);
      } else {
        s[j] = node;
        w[j] = 0.f;
      }
    }
    float v[16];
#pragma unroll
    for (int j = 0; j < 16; ++j) v[j] = t[s[j] * FD + f];
#pragma unroll
    for (int j = 0; j < 16; ++j) acc = fmaf(v[j], w[j], acc);
  }
  return acc;
}

// One block (128 threads) per node: aggregation + bias (+relu).
__global__ __launch_bounds__(128) void k_agg(const float* __restrict__ t,
                                             const int* __restrict__ ptr,
                                             const int2* __restrict__ sn,
                                             const float* __restrict__ dis,
                                             const float* __restrict__ bias,
                                             float* __restrict__ out, int relu) {
  int node = blockIdx.x;
  int f = threadIdx.x;
  float acc = agg_acc(t, ptr, sn, dis, node, f) + bias[f];
  if (relu) acc = fmaxf(acc, 0.f);
  out[node * FD + f] = acc;
}

// Last layer: aggregation + b3, then fused h @ Wlin + blin -> out[node][16].
__global__ __launch_bounds__(128) void k_agg_lin(const float* __restrict__ t,
                                                 const int* __restrict__ ptr,
                                                 const int2* __restrict__ sn,
                                                 const float* __restrict__ dis,
                                                 const float* __restrict__ b3,
                                                 const float* __restrict__ Wl,
                                                 const float* __restrict__ bl,
                                                 float* __restrict__ out) {
  __shared__ float hl[FD];
  __shared__ float part[8][NCLS];
  int node = blockIdx.x;
  int f = threadIdx.x;
  hl[f] = agg_acc(t, ptr, sn, dis, node, f) + b3[f];
  __syncthreads();
  int c = f & 15, p = f >> 4;  // 8 partials x 16 cols
  float s = 0.f;
#pragma unroll
  for (int k = 0; k < 16; ++k)
    s = fmaf(hl[p * 16 + k], Wl[(p * 16 + k) * NCLS + c], s);
  part[p][c] = s;
  __syncthreads();
  if (f < NCLS) {
    float r = bl[f];
#pragma unroll
    for (int q = 0; q < 8; ++q) r += part[q][f];
    out[node * NCLS + f] = r;
  }
}

extern "C" void kernel_launch(void* const* d_in, const int* in_sizes, int n_in,
                              void* d_out, int out_size, void* d_ws, size_t ws_size,
                              hipStream_t stream) {
  const float* x  = (const float*)d_in[0];
  const int*   ei = (const int*)d_in[1];
  const float* W1 = (const float*)d_in[2];
  const float* b1 = (const float*)d_in[3];
  const float* W2 = (const float*)d_in[4];
  const float* b2 = (const float*)d_in[5];
  const float* W3 = (const float*)d_in[6];
  const float* b3 = (const float*)d_in[7];
  const float* Wl = (const float*)d_in[8];
  const float* bl = (const float*)d_in[9];
  float* out = (float*)d_out;

  const int n = in_sizes[0] / FD;      // 50000
  const int e = in_sizes[1] / 2;       // 600000
  const int* src = ei;                 // edge_index[0]
  const int* dst = ei + e;             // edge_index[1]

  // workspace carve (all 4/8-byte types)
  float* bufT = (float*)d_ws;                  // n*FD
  float* bufH = bufT + (size_t)n * FD;         // n*FD
  int*   degi = (int*)(bufH + (size_t)n * FD); // n
  float* dis  = (float*)(degi + n);            // n
  int*   ptr  = (int*)(dis + n);               // n+1
  int*   cur  = ptr + n + 1;                   // n
  int*   bsum = cur + n;                       // <=64
  int2*  sn   = (int2*)(((uintptr_t)(bsum + 64) + 15) & ~(uintptr_t)15);  // e pairs

  const int gn = (n + 255) / 256;
  const int ge = (e + 255) / 256;
  const int nb = (n + 1023) / 1024;

  k_init_deg<<<gn, 256, 0, stream>>>(degi, n);
  k_count<<<ge, 256, 0, stream>>>(dst, degi, e);
  k_dis<<<gn, 256, 0, stream>>>(degi, dis, n);
  k_scanA<<<nb, 1024, 0, stream>>>(degi, ptr, bsum, n);
  k_scanB<<<1, 64, 0, stream>>>(bsum, nb);
  k_scanC<<<gn, 256, 0, stream>>>(ptr, cur, bsum, n, e);
  k_fill<<<ge, 256, 0, stream>>>(src, dst, cur, dis, sn, e);

  const int gg = n / 16;  // 3125 (n divisible by 16)

  k_gemm128<<<gg, 128, 0, stream>>>(x, W1, bufT);
  k_agg<<<n, 128, 0, stream>>>(bufT, ptr, sn, dis, b1, bufH, 1);
  k_gemm128<<<gg, 128, 0, stream>>>(bufH, W2, bufT);
  k_agg<<<n, 128, 0, stream>>>(bufT, ptr, sn, dis, b2, bufH, 1);
  k_gemm128<<<gg, 128, 0, stream>>>(bufH, W3, bufT);
  k_agg_lin<<<n, 128, 0, stream>>>(bufT, ptr, sn, dis, b3, Wl, bl, out);
}

// Round 4
// 426.555 us; speedup vs baseline: 1.3499x; 1.3499x over previous
//
#include <hip/hip_runtime.h>

// 3-layer GCN (PyG GCNConv semantics): deg/norm build -> CSR by dst ->
// per layer: GEMM (N x 128 @ 128 x 128) then CSR aggregation + bias (+relu),
// final 128->16 linear fused into the last aggregation. All fp32.
//
// R4 GEMM: 4 cols x 8 rows per thread (each 16B A-read feeds 16 FMAs, not 4).
// W staged once in LDS as float4[k][colgroup]; A read as lane-varying VMEM
// float4 (L1 broadcast across the 32 lanes of a row-group) — avoids both the
// R2 ds_read flood and the R3 scalar-load serialization.

#define FD 128
#define NCLS 16

__global__ __launch_bounds__(256) void k_init_deg(int* __restrict__ degi, int n) {
  int i = blockIdx.x * 256 + threadIdx.x;
  if (i < n) degi[i] = 1;  // self-loop
}

__global__ __launch_bounds__(256) void k_count(const int* __restrict__ dst,
                                               int* __restrict__ degi, int e) {
  int i = blockIdx.x * 256 + threadIdx.x;
  if (i < e) atomicAdd(&degi[dst[i]], 1);
}

__global__ __launch_bounds__(256) void k_dis(const int* __restrict__ degi,
                                             float* __restrict__ dis, int n) {
  int i = blockIdx.x * 256 + threadIdx.x;
  if (i < n) dis[i] = rsqrtf((float)degi[i]);
}

// Phase A: per-1024-chunk exclusive scan of (deg-1) = in-edge count
__global__ __launch_bounds__(1024) void k_scanA(const int* __restrict__ degi,
                                                int* __restrict__ ptr,
                                                int* __restrict__ bsum, int n) {
  __shared__ int buf[1024];
  int tid = threadIdx.x;
  int i = blockIdx.x * 1024 + tid;
  int v = (i < n) ? (degi[i] - 1) : 0;
  buf[tid] = v;
  __syncthreads();
  for (int off = 1; off < 1024; off <<= 1) {
    int t = (tid >= off) ? buf[tid - off] : 0;
    __syncthreads();
    buf[tid] += t;
    __syncthreads();
  }
  if (i < n) ptr[i] = buf[tid] - v;  // local exclusive
  if (tid == 1023) bsum[blockIdx.x] = buf[1023];
}

// Phase B: tiny serial scan of ~49 block sums
__global__ void k_scanB(int* __restrict__ bsum, int nb) {
  if (threadIdx.x == 0 && blockIdx.x == 0) {
    int run = 0;
    for (int b = 0; b < nb; ++b) { int t = bsum[b]; bsum[b] = run; run += t; }
  }
}

// Phase C: add chunk offsets, init fill cursors, write ptr[n]
__global__ __launch_bounds__(256) void k_scanC(int* __restrict__ ptr,
                                               int* __restrict__ cur,
                                               const int* __restrict__ bsum,
                                               int n, int e) {
  int i = blockIdx.x * 256 + threadIdx.x;
  if (i < n) {
    int p = ptr[i] + bsum[i >> 10];
    ptr[i] = p;
    cur[i] = p;
  }
  if (i == 0) ptr[n] = e;
}

__global__ __launch_bounds__(256) void k_fill(const int* __restrict__ src,
                                              const int* __restrict__ dst,
                                              int* __restrict__ cur,
                                              const float* __restrict__ dis,
                                              int2* __restrict__ sn, int e) {
  int i = blockIdx.x * 256 + threadIdx.x;
  if (i < e) {
    int s = src[i], d = dst[i];
    int p = atomicAdd(&cur[d], 1);
    sn[p] = make_int2(s, __float_as_int(dis[s] * dis[d]));
  }
}

// GEMM: out[64-row tile][128] = in @ W. 256 threads: rg=tid>>5 (8 rows each),
// cg=tid&31 (4 contiguous cols). W in LDS once; A via VMEM broadcast.
__global__ __launch_bounds__(256) void k_gemm128(const float* __restrict__ in,
                                                 const float* __restrict__ W,
                                                 float* __restrict__ out, int n) {
  __shared__ float4 wl[FD][32];  // 64 KB: wl[k][cg] = W[k][cg*4 .. cg*4+3]
  int tid = threadIdx.x;
  for (int i = tid; i < FD * 32; i += 256)
    ((float4*)wl)[i] = reinterpret_cast<const float4*>(W)[i];
  __syncthreads();

  int cg = tid & 31;
  int rg = tid >> 5;
  int rbase = blockIdx.x * 64 + rg * 8;
  const float* rowp[8];
#pragma unroll
  for (int r = 0; r < 8; ++r) {
    int row = rbase + r;
    if (row > n - 1) row = n - 1;  // clamp: safe OOB-free reads for tail tile
    rowp[r] = in + (size_t)row * FD;
  }
  float4 acc[8];
#pragma unroll
  for (int r = 0; r < 8; ++r) acc[r] = make_float4(0.f, 0.f, 0.f, 0.f);

  for (int k = 0; k < FD; k += 4) {
    float4 w0 = wl[k + 0][cg];
    float4 w1 = wl[k + 1][cg];
    float4 w2 = wl[k + 2][cg];
    float4 w3 = wl[k + 3][cg];
#pragma unroll
    for (int r = 0; r < 8; ++r) {
      float4 a = *reinterpret_cast<const float4*>(rowp[r] + k);
      acc[r].x = fmaf(a.x, w0.x, acc[r].x);
      acc[r].y = fmaf(a.x, w0.y, acc[r].y);
      acc[r].z = fmaf(a.x, w0.z, acc[r].z);
      acc[r].w = fmaf(a.x, w0.w, acc[r].w);
      acc[r].x = fmaf(a.y, w1.x, acc[r].x);
      acc[r].y = fmaf(a.y, w1.y, acc[r].y);
      acc[r].z = fmaf(a.y, w1.z, acc[r].z);
      acc[r].w = fmaf(a.y, w1.w, acc[r].w);
      acc[r].x = fmaf(a.z, w2.x, acc[r].x);
      acc[r].y = fmaf(a.z, w2.y, acc[r].y);
      acc[r].z = fmaf(a.z, w2.z, acc[r].z);
      acc[r].w = fmaf(a.z, w2.w, acc[r].w);
      acc[r].x = fmaf(a.w, w3.x, acc[r].x);
      acc[r].y = fmaf(a.w, w3.y, acc[r].y);
      acc[r].z = fmaf(a.w, w3.z, acc[r].z);
      acc[r].w = fmaf(a.w, w3.w, acc[r].w);
    }
  }
#pragma unroll
  for (int r = 0; r < 8; ++r) {
    int row = rbase + r;
    if (row < n)
      *reinterpret_cast<float4*>(&out[(size_t)row * FD + cg * 4]) = acc[r];
  }
}

// Batched CSR aggregation: 16 independent gathers in flight per thread.
__device__ __forceinline__ float agg_acc(const float* __restrict__ t,
                                         const int* __restrict__ ptr,
                                         const int2* __restrict__ sn,
                                         const float* __restrict__ dis,
                                         int node, int f) {
  float d = dis[node];
  float acc = t[node * FD + f] * (d * d);
  int e0 = ptr[node], e1 = ptr[node + 1];
  for (int e = e0; e < e1; e += 16) {
    int s[16];
    float w[16];
#pragma unroll
    for (int j = 0; j < 16; ++j) {
      if (e + j < e1) {
        int2 p = sn[e + j];
        s[j] = p.x;
        w[j] = __int_as_float(p.y);
      } else {
        s[j] = node;
        w[j] = 0.f;
      }
    }
    float v[16];
#pragma unroll
    for (int j = 0; j < 16; ++j) v[j] = t[s[j] * FD + f];
#pragma unroll
    for (int j = 0; j < 16; ++j) acc = fmaf(v[j], w[j], acc);
  }
  return acc;
}

// One block (128 threads) per node: aggregation + bias (+relu).
__global__ __launch_bounds__(128) void k_agg(const float* __restrict__ t,
                                             const int* __restrict__ ptr,
                                             const int2* __restrict__ sn,
                                             const float* __restrict__ dis,
                                             const float* __restrict__ bias,
                                             float* __restrict__ out, int relu) {
  int node = blockIdx.x;
  int f = threadIdx.x;
  float acc = agg_acc(t, ptr, sn, dis, node, f) + bias[f];
  if (relu) acc = fmaxf(acc, 0.f);
  out[node * FD + f] = acc;
}

// Last layer: aggregation + b3, then fused h @ Wlin + blin -> out[node][16].
__global__ __launch_bounds__(128) void k_agg_lin(const float* __restrict__ t,
                                                 const int* __restrict__ ptr,
                                                 const int2* __restrict__ sn,
                                                 const float* __restrict__ dis,
                                                 const float* __restrict__ b3,
                                                 const float* __restrict__ Wl,
                                                 const float* __restrict__ bl,
                                                 float* __restrict__ out) {
  __shared__ float hl[FD];
  __shared__ float part[8][NCLS];
  int node = blockIdx.x;
  int f = threadIdx.x;
  hl[f] = agg_acc(t, ptr, sn, dis, node, f) + b3[f];
  __syncthreads();
  int c = f & 15, p = f >> 4;  // 8 partials x 16 cols
  float s = 0.f;
#pragma unroll
  for (int k = 0; k < 16; ++k)
    s = fmaf(hl[p * 16 + k], Wl[(p * 16 + k) * NCLS + c], s);
  part[p][c] = s;
  __syncthreads();
  if (f < NCLS) {
    float r = bl[f];
#pragma unroll
    for (int q = 0; q < 8; ++q) r += part[q][f];
    out[node * NCLS + f] = r;
  }
}

extern "C" void kernel_launch(void* const* d_in, const int* in_sizes, int n_in,
                              void* d_out, int out_size, void* d_ws, size_t ws_size,
                              hipStream_t stream) {
  const float* x  = (const float*)d_in[0];
  const int*   ei = (const int*)d_in[1];
  const float* W1 = (const float*)d_in[2];
  const float* b1 = (const float*)d_in[3];
  const float* W2 = (const float*)d_in[4];
  const float* b2 = (const float*)d_in[5];
  const float* W3 = (const float*)d_in[6];
  const float* b3 = (const float*)d_in[7];
  const float* Wl = (const float*)d_in[8];
  const float* bl = (const float*)d_in[9];
  float* out = (float*)d_out;

  const int n = in_sizes[0] / FD;      // 50000
  const int e = in_sizes[1] / 2;       // 600000
  const int* src = ei;                 // edge_index[0]
  const int* dst = ei + e;             // edge_index[1]

  // workspace carve (all 4/8-byte types)
  float* bufT = (float*)d_ws;                  // n*FD
  float* bufH = bufT + (size_t)n * FD;         // n*FD
  int*   degi = (int*)(bufH + (size_t)n * FD); // n
  float* dis  = (float*)(degi + n);            // n
  int*   ptr  = (int*)(dis + n);               // n+1
  int*   cur  = ptr + n + 1;                   // n
  int*   bsum = cur + n;                       // <=64
  int2*  sn   = (int2*)(((uintptr_t)(bsum + 64) + 15) & ~(uintptr_t)15);  // e pairs

  const int gn = (n + 255) / 256;
  const int ge = (e + 255) / 256;
  const int nb = (n + 1023) / 1024;

  k_init_deg<<<gn, 256, 0, stream>>>(degi, n);
  k_count<<<ge, 256, 0, stream>>>(dst, degi, e);
  k_dis<<<gn, 256, 0, stream>>>(degi, dis, n);
  k_scanA<<<nb, 1024, 0, stream>>>(degi, ptr, bsum, n);
  k_scanB<<<1, 64, 0, stream>>>(bsum, nb);
  k_scanC<<<gn, 256, 0, stream>>>(ptr, cur, bsum, n, e);
  k_fill<<<ge, 256, 0, stream>>>(src, dst, cur, dis, sn, e);

  const int gG = (n + 63) / 64;  // 782 tiles of 64 rows

  k_gemm128<<<gG, 256, 0, stream>>>(x, W1, bufT, n);
  k_agg<<<n, 128, 0, stream>>>(bufT, ptr, sn, dis, b1, bufH, 1);
  k_gemm128<<<gG, 256, 0, stream>>>(bufH, W2, bufT, n);
  k_agg<<<n, 128, 0, stream>>>(bufT, ptr, sn, dis, b2, bufH, 1);
  k_gemm128<<<gG, 256, 0, stream>>>(bufH, W3, bufT, n);
  k_agg_lin<<<n, 128, 0, stream>>>(bufT, ptr, sn, dis, b3, Wl, bl, out);
}

// Round 5
// 386.471 us; speedup vs baseline: 1.4899x; 1.1037x over previous
//
#include <hip/hip_runtime.h>
#include <hip/hip_fp16.h>

// 3-layer GCN (PyG GCNConv semantics): deg/norm build -> CSR by dst ->
// per layer: GEMM (N x 128 @ 128 x 128, fp32 in, fp16 out) then CSR
// aggregation (fp16 gather, fp32 accumulate) + bias (+relu), final 128->16
// linear fused into the last aggregation.
//
// R5: (a) GEMM tile 64x64 (32KB LDS -> 5 blocks/CU, grid 1564) with
// register-double-buffered A loads; (b) t stored fp16 -> gather traffic
// halves (agg was L3-throughput-bound at ~3 TB/s of fetch).

#define FD 128
#define NCLS 16

__global__ __launch_bounds__(256) void k_init_deg(int* __restrict__ degi, int n) {
  int i = blockIdx.x * 256 + threadIdx.x;
  if (i < n) degi[i] = 1;  // self-loop
}

__global__ __launch_bounds__(256) void k_count(const int* __restrict__ dst,
                                               int* __restrict__ degi, int e) {
  int i = blockIdx.x * 256 + threadIdx.x;
  if (i < e) atomicAdd(&degi[dst[i]], 1);
}

__global__ __launch_bounds__(256) void k_dis(const int* __restrict__ degi,
                                             float* __restrict__ dis, int n) {
  int i = blockIdx.x * 256 + threadIdx.x;
  if (i < n) dis[i] = rsqrtf((float)degi[i]);
}

// Phase A: per-1024-chunk exclusive scan of (deg-1) = in-edge count
__global__ __launch_bounds__(1024) void k_scanA(const int* __restrict__ degi,
                                                int* __restrict__ ptr,
                                                int* __restrict__ bsum, int n) {
  __shared__ int buf[1024];
  int tid = threadIdx.x;
  int i = blockIdx.x * 1024 + tid;
  int v = (i < n) ? (degi[i] - 1) : 0;
  buf[tid] = v;
  __syncthreads();
  for (int off = 1; off < 1024; off <<= 1) {
    int t = (tid >= off) ? buf[tid - off] : 0;
    __syncthreads();
    buf[tid] += t;
    __syncthreads();
  }
  if (i < n) ptr[i] = buf[tid] - v;  // local exclusive
  if (tid == 1023) bsum[blockIdx.x] = buf[1023];
}

// Phase B: tiny serial scan of ~49 block sums
__global__ void k_scanB(int* __restrict__ bsum, int nb) {
  if (threadIdx.x == 0 && blockIdx.x == 0) {
    int run = 0;
    for (int b = 0; b < nb; ++b) { int t = bsum[b]; bsum[b] = run; run += t; }
  }
}

// Phase C: add chunk offsets, init fill cursors, write ptr[n]
__global__ __launch_bounds__(256) void k_scanC(int* __restrict__ ptr,
                                               int* __restrict__ cur,
                                               const int* __restrict__ bsum,
                                               int n, int e) {
  int i = blockIdx.x * 256 + threadIdx.x;
  if (i < n) {
    int p = ptr[i] + bsum[i >> 10];
    ptr[i] = p;
    cur[i] = p;
  }
  if (i == 0) ptr[n] = e;
}

__global__ __launch_bounds__(256) void k_fill(const int* __restrict__ src,
                                              const int* __restrict__ dst,
                                              int* __restrict__ cur,
                                              const float* __restrict__ dis,
                                              int2* __restrict__ sn, int e) {
  int i = blockIdx.x * 256 + threadIdx.x;
  if (i < e) {
    int s = src[i], d = dst[i];
    int p = atomicAdd(&cur[d], 1);
    sn[p] = make_int2(s, __float_as_int(dis[s] * dis[d]));
  }
}

// GEMM: 64 rows x 64 cols per block, 256 threads, thread = 4 rows x 4 cols.
// W-chunk (128k x 64c = 32KB) in LDS; A register-double-buffered VMEM float4.
// Output converted to fp16.
__global__ __launch_bounds__(256) void k_gemm128h(const float* __restrict__ in,
                                                  const float* __restrict__ W,
                                                  __half* __restrict__ outh, int n) {
  __shared__ float4 wl[FD][16];  // 32 KB: wl[k][cg] = W[k][cbase+cg*4 ..+3]
  int tid = threadIdx.x;
  int cbase = blockIdx.y * 64;
  int cb4 = cbase >> 2;
  const float4* W4 = reinterpret_cast<const float4*>(W);
  for (int i = tid; i < FD * 16; i += 256) {
    int k = i >> 4, cg = i & 15;
    wl[k][cg] = W4[k * 32 + cb4 + cg];
  }
  __syncthreads();

  int cg = tid & 15;       // 4 cols
  int rg = tid >> 4;       // 4 rows
  int rbase = blockIdx.x * 64 + rg * 4;
  const float* rowp[4];
#pragma unroll
  for (int r = 0; r < 4; ++r) {
    int row = rbase + r;
    if (row > n - 1) row = n - 1;  // clamp: safe reads for tail tile
    rowp[r] = in + (size_t)row * FD;
  }
  float4 acc[4];
#pragma unroll
  for (int r = 0; r < 4; ++r) acc[r] = make_float4(0.f, 0.f, 0.f, 0.f);

  float4 a_cur[4];
#pragma unroll
  for (int r = 0; r < 4; ++r) a_cur[r] = *reinterpret_cast<const float4*>(rowp[r]);

  for (int k = 0; k < FD; k += 4) {
    int kn = (k + 4 < FD) ? k + 4 : k;  // tail: harmless re-read, no OOB
    float4 a_nxt[4];
#pragma unroll
    for (int r = 0; r < 4; ++r)
      a_nxt[r] = *reinterpret_cast<const float4*>(rowp[r] + kn);
    float4 w0 = wl[k + 0][cg];
    float4 w1 = wl[k + 1][cg];
    float4 w2 = wl[k + 2][cg];
    float4 w3 = wl[k + 3][cg];
#pragma unroll
    for (int r = 0; r < 4; ++r) {
      float4 a = a_cur[r];
      acc[r].x = fmaf(a.x, w0.x, acc[r].x);
      acc[r].y = fmaf(a.x, w0.y, acc[r].y);
      acc[r].z = fmaf(a.x, w0.z, acc[r].z);
      acc[r].w = fmaf(a.x, w0.w, acc[r].w);
      acc[r].x = fmaf(a.y, w1.x, acc[r].x);
      acc[r].y = fmaf(a.y, w1.y, acc[r].y);
      acc[r].z = fmaf(a.y, w1.z, acc[r].z);
      acc[r].w = fmaf(a.y, w1.w, acc[r].w);
      acc[r].x = fmaf(a.z, w2.x, acc[r].x);
      acc[r].y = fmaf(a.z, w2.y, acc[r].y);
      acc[r].z = fmaf(a.z, w2.z, acc[r].z);
      acc[r].w = fmaf(a.z, w2.w, acc[r].w);
      acc[r].x = fmaf(a.w, w3.x, acc[r].x);
      acc[r].y = fmaf(a.w, w3.y, acc[r].y);
      acc[r].z = fmaf(a.w, w3.z, acc[r].z);
      acc[r].w = fmaf(a.w, w3.w, acc[r].w);
      a_cur[r] = a_nxt[r];
    }
  }

#pragma unroll
  for (int r = 0; r < 4; ++r) {
    int row = rbase + r;
    if (row < n) {
      __half h[4];
      h[0] = __float2half_rn(acc[r].x);
      h[1] = __float2half_rn(acc[r].y);
      h[2] = __float2half_rn(acc[r].z);
      h[3] = __float2half_rn(acc[r].w);
      *reinterpret_cast<uint2*>(&outh[(size_t)row * FD + cbase + cg * 4]) =
          *reinterpret_cast<uint2*>(h);
    }
  }
}

// Batched CSR aggregation: 16 independent fp16 gathers in flight per thread,
// fp32 accumulate. Short batches padded with (node, w=0).
__device__ __forceinline__ float agg_acc(const __half* __restrict__ t,
                                         const int* __restrict__ ptr,
                                         const int2* __restrict__ sn,
                                         const float* __restrict__ dis,
                                         int node, int f) {
  float d = dis[node];
  float acc = __half2float(t[(size_t)node * FD + f]) * (d * d);
  int e0 = ptr[node], e1 = ptr[node + 1];
  for (int e = e0; e < e1; e += 16) {
    int s[16];
    float w[16];
#pragma unroll
    for (int j = 0; j < 16; ++j) {
      if (e + j < e1) {
        int2 p = sn[e + j];
        s[j] = p.x;
        w[j] = __int_as_float(p.y);
      } else {
        s[j] = node;
        w[j] = 0.f;
      }
    }
    __half v[16];
#pragma unroll
    for (int j = 0; j < 16; ++j) v[j] = t[(size_t)s[j] * FD + f];
#pragma unroll
    for (int j = 0; j < 16; ++j) acc = fmaf(__half2float(v[j]), w[j], acc);
  }
  return acc;
}

// One block (128 threads) per node: aggregation + bias (+relu), fp32 out.
__global__ __launch_bounds__(128) void k_agg(const __half* __restrict__ t,
                                             const int* __restrict__ ptr,
                                             const int2* __restrict__ sn,
                                             const float* __restrict__ dis,
                                             const float* __restrict__ bias,
                                             float* __restrict__ out, int relu) {
  int node = blockIdx.x;
  int f = threadIdx.x;
  float acc = agg_acc(t, ptr, sn, dis, node, f) + bias[f];
  if (relu) acc = fmaxf(acc, 0.f);
  out[(size_t)node * FD + f] = acc;
}

// Last layer: aggregation + b3, then fused h @ Wlin + blin -> out[node][16].
__global__ __launch_bounds__(128) void k_agg_lin(const __half* __restrict__ t,
                                                 const int* __restrict__ ptr,
                                                 const int2* __restrict__ sn,
                                                 const float* __restrict__ dis,
                                                 const float* __restrict__ b3,
                                                 const float* __restrict__ Wl,
                                                 const float* __restrict__ bl,
                                                 float* __restrict__ out) {
  __shared__ float hl[FD];
  __shared__ float part[8][NCLS];
  int node = blockIdx.x;
  int f = threadIdx.x;
  hl[f] = agg_acc(t, ptr, sn, dis, node, f) + b3[f];
  __syncthreads();
  int c = f & 15, p = f >> 4;  // 8 partials x 16 cols
  float s = 0.f;
#pragma unroll
  for (int k = 0; k < 16; ++k)
    s = fmaf(hl[p * 16 + k], Wl[(p * 16 + k) * NCLS + c], s);
  part[p][c] = s;
  __syncthreads();
  if (f < NCLS) {
    float r = bl[f];
#pragma unroll
    for (int q = 0; q < 8; ++q) r += part[q][f];
    out[node * NCLS + f] = r;
  }
}

extern "C" void kernel_launch(void* const* d_in, const int* in_sizes, int n_in,
                              void* d_out, int out_size, void* d_ws, size_t ws_size,
                              hipStream_t stream) {
  const float* x  = (const float*)d_in[0];
  const int*   ei = (const int*)d_in[1];
  const float* W1 = (const float*)d_in[2];
  const float* b1 = (const float*)d_in[3];
  const float* W2 = (const float*)d_in[4];
  const float* b2 = (const float*)d_in[5];
  const float* W3 = (const float*)d_in[6];
  const float* b3 = (const float*)d_in[7];
  const float* Wl = (const float*)d_in[8];
  const float* bl = (const float*)d_in[9];
  float* out = (float*)d_out;

  const int n = in_sizes[0] / FD;      // 50000
  const int e = in_sizes[1] / 2;       // 600000
  const int* src = ei;                 // edge_index[0]
  const int* dst = ei + e;             // edge_index[1]

  // workspace carve: th (half, n*FD) | bufH (float, n*FD) | ints | sn
  __half* th  = (__half*)d_ws;                       // n*FD halves (12.8 MB)
  float* bufH = (float*)(th + (size_t)n * FD);       // n*FD floats
  int*   degi = (int*)(bufH + (size_t)n * FD);       // n
  float* dis  = (float*)(degi + n);                  // n
  int*   ptr  = (int*)(dis + n);                     // n+1
  int*   cur  = ptr + n + 1;                         // n
  int*   bsum = cur + n;                             // <=64
  int2*  sn   = (int2*)(((uintptr_t)(bsum + 64) + 15) & ~(uintptr_t)15);  // e pairs

  const int gn = (n + 255) / 256;
  const int ge = (e + 255) / 256;
  const int nb = (n + 1023) / 1024;

  k_init_deg<<<gn, 256, 0, stream>>>(degi, n);
  k_count<<<ge, 256, 0, stream>>>(dst, degi, e);
  k_dis<<<gn, 256, 0, stream>>>(degi, dis, n);
  k_scanA<<<nb, 1024, 0, stream>>>(degi, ptr, bsum, n);
  k_scanB<<<1, 64, 0, stream>>>(bsum, nb);
  k_scanC<<<gn, 256, 0, stream>>>(ptr, cur, bsum, n, e);
  k_fill<<<ge, 256, 0, stream>>>(src, dst, cur, dis, sn, e);

  dim3 gG((n + 63) / 64, 2);  // 782 row-tiles x 2 col-halves

  k_gemm128h<<<gG, 256, 0, stream>>>(x, W1, th, n);
  k_agg<<<n, 128, 0, stream>>>(th, ptr, sn, dis, b1, bufH, 1);
  k_gemm128h<<<gG, 256, 0, stream>>>(bufH, W2, th, n);
  k_agg<<<n, 128, 0, stream>>>(th, ptr, sn, dis, b2, bufH, 1);
  k_gemm128h<<<gG, 256, 0, stream>>>(bufH, W3, th, n);
  k_agg_lin<<<n, 128, 0, stream>>>(th, ptr, sn, dis, b3, Wl, bl, out);
}

// Round 8
// 374.156 us; speedup vs baseline: 1.5389x; 1.0329x over previous
//
#include <hip/hip_runtime.h>
#include <hip/hip_fp16.h>

// 3-layer GCN (PyG GCNConv semantics): deg/norm build -> CSR by dst ->
// per layer: GEMM (N x 128 @ 128 x 128, fp32 in, fp16 out) then CSR
// aggregation (fp16 gather, fp32 accumulate) + bias (+relu), final 128->16
// linear fused into the last aggregation.
//
// R6 (3rd submit; two broker-side failures, kernel never ran): aggregation =
// 1 wave per node, 4 features/lane (ushort4), two edges per wave VMEM
// instruction (half-wave each) -> 1 VMEM instr per edge vs 4 before.
// Evidence: fp16 halved bytes with no time change; batching gave no change;
// => agg is VMEM-request-rate bound, so cut requests.

#define FD 128
#define NCLS 16

__global__ __launch_bounds__(256) void k_init_deg(int* __restrict__ degi, int n) {
  int i = blockIdx.x * 256 + threadIdx.x;
  if (i < n) degi[i] = 1;  // self-loop
}

__global__ __launch_bounds__(256) void k_count(const int* __restrict__ dst,
                                               int* __restrict__ degi, int e) {
  int i = blockIdx.x * 256 + threadIdx.x;
  if (i < e) atomicAdd(&degi[dst[i]], 1);
}

__global__ __launch_bounds__(256) void k_dis(const int* __restrict__ degi,
                                             float* __restrict__ dis, int n) {
  int i = blockIdx.x * 256 + threadIdx.x;
  if (i < n) dis[i] = rsqrtf((float)degi[i]);
}

// Phase A: per-1024-chunk exclusive scan of (deg-1) = in-edge count
__global__ __launch_bounds__(1024) void k_scanA(const int* __restrict__ degi,
                                                int* __restrict__ ptr,
                                                int* __restrict__ bsum, int n) {
  __shared__ int buf[1024];
  int tid = threadIdx.x;
  int i = blockIdx.x * 1024 + tid;
  int v = (i < n) ? (degi[i] - 1) : 0;
  buf[tid] = v;
  __syncthreads();
  for (int off = 1; off < 1024; off <<= 1) {
    int t = (tid >= off) ? buf[tid - off] : 0;
    __syncthreads();
    buf[tid] += t;
    __syncthreads();
  }
  if (i < n) ptr[i] = buf[tid] - v;  // local exclusive
  if (tid == 1023) bsum[blockIdx.x] = buf[1023];
}

// Phase B: tiny serial scan of ~49 block sums
__global__ void k_scanB(int* __restrict__ bsum, int nb) {
  if (threadIdx.x == 0 && blockIdx.x == 0) {
    int run = 0;
    for (int b = 0; b < nb; ++b) { int t = bsum[b]; bsum[b] = run; run += t; }
  }
}

// Phase C: add chunk offsets, init fill cursors, write ptr[n]
__global__ __launch_bounds__(256) void k_scanC(int* __restrict__ ptr,
                                               int* __restrict__ cur,
                                               const int* __restrict__ bsum,
                                               int n, int e) {
  int i = blockIdx.x * 256 + threadIdx.x;
  if (i < n) {
    int p = ptr[i] + bsum[i >> 10];
    ptr[i] = p;
    cur[i] = p;
  }
  if (i == 0) ptr[n] = e;
}

__global__ __launch_bounds__(256) void k_fill(const int* __restrict__ src,
                                              const int* __restrict__ dst,
                                              int* __restrict__ cur,
                                              const float* __restrict__ dis,
                                              int2* __restrict__ sn, int e) {
  int i = blockIdx.x * 256 + threadIdx.x;
  if (i < e) {
    int s = src[i], d = dst[i];
    int p = atomicAdd(&cur[d], 1);
    sn[p] = make_int2(s, __float_as_int(dis[s] * dis[d]));
  }
}

// GEMM: 64 rows x 64 cols per block, 256 threads, thread = 4 rows x 4 cols.
// W-chunk (32KB) in LDS; A register-double-buffered VMEM float4. fp16 out.
__global__ __launch_bounds__(256) void k_gemm128h(const float* __restrict__ in,
                                                  const float* __restrict__ W,
                                                  __half* __restrict__ outh, int n) {
  __shared__ float4 wl[FD][16];  // 32 KB
  int tid = threadIdx.x;
  int cbase = blockIdx.y * 64;
  int cb4 = cbase >> 2;
  const float4* W4 = reinterpret_cast<const float4*>(W);
  for (int i = tid; i < FD * 16; i += 256) {
    int k = i >> 4, cg = i & 15;
    wl[k][cg] = W4[k * 32 + cb4 + cg];
  }
  __syncthreads();

  int cg = tid & 15;       // 4 cols
  int rg = tid >> 4;       // 4 rows
  int rbase = blockIdx.x * 64 + rg * 4;
  const float* rowp[4];
#pragma unroll
  for (int r = 0; r < 4; ++r) {
    int row = rbase + r;
    if (row > n - 1) row = n - 1;  // clamp: safe reads for tail tile
    rowp[r] = in + (size_t)row * FD;
  }
  float4 acc[4];
#pragma unroll
  for (int r = 0; r < 4; ++r) acc[r] = make_float4(0.f, 0.f, 0.f, 0.f);

  float4 a_cur[4];
#pragma unroll
  for (int r = 0; r < 4; ++r) a_cur[r] = *reinterpret_cast<const float4*>(rowp[r]);

  for (int k = 0; k < FD; k += 4) {
    int kn = (k + 4 < FD) ? k + 4 : k;  // tail: harmless re-read, no OOB
    float4 a_nxt[4];
#pragma unroll
    for (int r = 0; r < 4; ++r)
      a_nxt[r] = *reinterpret_cast<const float4*>(rowp[r] + kn);
    float4 w0 = wl[k + 0][cg];
    float4 w1 = wl[k + 1][cg];
    float4 w2 = wl[k + 2][cg];
    float4 w3 = wl[k + 3][cg];
#pragma unroll
    for (int r = 0; r < 4; ++r) {
      float4 a = a_cur[r];
      acc[r].x = fmaf(a.x, w0.x, acc[r].x);
      acc[r].y = fmaf(a.x, w0.y, acc[r].y);
      acc[r].z = fmaf(a.x, w0.z, acc[r].z);
      acc[r].w = fmaf(a.x, w0.w, acc[r].w);
      acc[r].x = fmaf(a.y, w1.x, acc[r].x);
      acc[r].y = fmaf(a.y, w1.y, acc[r].y);
      acc[r].z = fmaf(a.y, w1.z, acc[r].z);
      acc[r].w = fmaf(a.y, w1.w, acc[r].w);
      acc[r].x = fmaf(a.z, w2.x, acc[r].x);
      acc[r].y = fmaf(a.z, w2.y, acc[r].y);
      acc[r].z = fmaf(a.z, w2.z, acc[r].z);
      acc[r].w = fmaf(a.z, w2.w, acc[r].w);
      acc[r].x = fmaf(a.w, w3.x, acc[r].x);
      acc[r].y = fmaf(a.w, w3.y, acc[r].y);
      acc[r].z = fmaf(a.w, w3.z, acc[r].z);
      acc[r].w = fmaf(a.w, w3.w, acc[r].w);
      a_cur[r] = a_nxt[r];
    }
  }

#pragma unroll
  for (int r = 0; r < 4; ++r) {
    int row = rbase + r;
    if (row < n) {
      __half h[4];
      h[0] = __float2half_rn(acc[r].x);
      h[1] = __float2half_rn(acc[r].y);
      h[2] = __float2half_rn(acc[r].z);
      h[3] = __float2half_rn(acc[r].w);
      *reinterpret_cast<uint2*>(&outh[(size_t)row * FD + cbase + cg * 4]) =
          *reinterpret_cast<uint2*>(h);
    }
  }
}

// Wave-level aggregation core: lane = (h = lane>>5 edge-parity, q = lane&31
// feature group of 4). Two edges per wave VMEM instruction. Returns, in o[4],
// the full edge-sum for features q*4..q*4+3 (valid in ALL lanes after the
// xor-32 shuffle reduce).
__device__ __forceinline__ void agg_wave(const __half* __restrict__ t,
                                         const int* __restrict__ ptr,
                                         const int2* __restrict__ sn,
                                         int node, int lane, float o[4]) {
  int h = lane >> 5;
  int q = lane & 31;
  float a0 = 0.f, a1 = 0.f, a2 = 0.f, a3 = 0.f;
  int e0 = ptr[node], e1 = ptr[node + 1];
  for (int base = e0; base < e1; base += 16) {
    int s[8];
    float w[8];
#pragma unroll
    for (int j = 0; j < 8; ++j) {
      int idx = base + 2 * j + h;
      if (idx < e1) {
        int2 p = sn[idx];   // broadcast across the 32 lanes of this half
        s[j] = p.x;
        w[j] = __int_as_float(p.y);
      } else {
        s[j] = node;        // pad: hot self row, weight 0
        w[j] = 0.f;
      }
    }
    ushort4 v[8];
#pragma unroll
    for (int j = 0; j < 8; ++j)
      v[j] = *reinterpret_cast<const ushort4*>(&t[(size_t)s[j] * FD + q * 4]);
#pragma unroll
    for (int j = 0; j < 8; ++j) {
      a0 = fmaf(__half2float(__ushort_as_half(v[j].x)), w[j], a0);
      a1 = fmaf(__half2float(__ushort_as_half(v[j].y)), w[j], a1);
      a2 = fmaf(__half2float(__ushort_as_half(v[j].z)), w[j], a2);
      a3 = fmaf(__half2float(__ushort_as_half(v[j].w)), w[j], a3);
    }
  }
  // combine the two edge-parity halves: every lane ends with the full sum
  o[0] = a0 + __shfl(a0, lane ^ 32, 64);
  o[1] = a1 + __shfl(a1, lane ^ 32, 64);
  o[2] = a2 + __shfl(a2, lane ^ 32, 64);
  o[3] = a3 + __shfl(a3, lane ^ 32, 64);
}

// 4 nodes per 256-thread block (1 wave per node): agg + bias (+relu), fp32 out.
__global__ __launch_bounds__(256) void k_agg(const __half* __restrict__ t,
                                             const int* __restrict__ ptr,
                                             const int2* __restrict__ sn,
                                             const float* __restrict__ dis,
                                             const float* __restrict__ bias,
                                             float* __restrict__ out, int relu) {
  int lane = threadIdx.x & 63;
  int node = blockIdx.x * 4 + (threadIdx.x >> 6);
  float d = dis[node];
  float dd = d * d;
  float o[4];
  agg_wave(t, ptr, sn, node, lane, o);
  if (lane < 32) {
    int q = lane;
    ushort4 sv = *reinterpret_cast<const ushort4*>(&t[(size_t)node * FD + q * 4]);
    float4 b = *reinterpret_cast<const float4*>(&bias[q * 4]);
    o[0] = fmaf(__half2float(__ushort_as_half(sv.x)), dd, o[0]) + b.x;
    o[1] = fmaf(__half2float(__ushort_as_half(sv.y)), dd, o[1]) + b.y;
    o[2] = fmaf(__half2float(__ushort_as_half(sv.z)), dd, o[2]) + b.z;
    o[3] = fmaf(__half2float(__ushort_as_half(sv.w)), dd, o[3]) + b.w;
    if (relu) {
      o[0] = fmaxf(o[0], 0.f);
      o[1] = fmaxf(o[1], 0.f);
      o[2] = fmaxf(o[2], 0.f);
      o[3] = fmaxf(o[3], 0.f);
    }
    float4 r = make_float4(o[0], o[1], o[2], o[3]);
    *reinterpret_cast<float4*>(&out[(size_t)node * FD + q * 4]) = r;
  }
}

// Last layer: agg + b3 into LDS, then fused h @ Wlin + blin -> out[node][16].
__global__ __launch_bounds__(256) void k_agg_lin(const __half* __restrict__ t,
                                                 const int* __restrict__ ptr,
                                                 const int2* __restrict__ sn,
                                                 const float* __restrict__ dis,
                                                 const float* __restrict__ b3,
                                                 const float* __restrict__ Wl,
                                                 const float* __restrict__ bl,
                                                 float* __restrict__ out) {
  __shared__ float hl[4][FD];
  int wid = threadIdx.x >> 6;
  int lane = threadIdx.x & 63;
  int node = blockIdx.x * 4 + wid;
  float d = dis[node];
  float dd = d * d;
  float o[4];
  agg_wave(t, ptr, sn, node, lane, o);
  if (lane < 32) {
    int q = lane;
    ushort4 sv = *reinterpret_cast<const ushort4*>(&t[(size_t)node * FD + q * 4]);
    float4 b = *reinterpret_cast<const float4*>(&b3[q * 4]);
    hl[wid][q * 4 + 0] = fmaf(__half2float(__ushort_as_half(sv.x)), dd, o[0]) + b.x;
    hl[wid][q * 4 + 1] = fmaf(__half2float(__ushort_as_half(sv.y)), dd, o[1]) + b.y;
    hl[wid][q * 4 + 2] = fmaf(__half2float(__ushort_as_half(sv.z)), dd, o[2]) + b.z;
    hl[wid][q * 4 + 3] = fmaf(__half2float(__ushort_as_half(sv.w)), dd, o[3]) + b.w;
  }
  __syncthreads();
  // 64 lanes: c = lane&15 (class), kc = lane>>4 (k-chunk of 32)
  int c = lane & 15, kc = lane >> 4;
  float s = 0.f;
#pragma unroll
  for (int k0 = 0; k0 < 32; ++k0) {
    int k = kc * 32 + k0;
    s = fmaf(hl[wid][k], Wl[k * NCLS + c], s);
  }
  s += __shfl(s, lane ^ 16, 64);
  s += __shfl(s, lane ^ 32, 64);
  if (lane < NCLS)
    out[(size_t)node * NCLS + lane] = s + bl[lane];
}

extern "C" void kernel_launch(void* const* d_in, const int* in_sizes, int n_in,
                              void* d_out, int out_size, void* d_ws, size_t ws_size,
                              hipStream_t stream) {
  const float* x  = (const float*)d_in[0];
  const int*   ei = (const int*)d_in[1];
  const float* W1 = (const float*)d_in[2];
  const float* b1 = (const float*)d_in[3];
  const float* W2 = (const float*)d_in[4];
  const float* b2 = (const float*)d_in[5];
  const float* W3 = (const float*)d_in[6];
  const float* b3 = (const float*)d_in[7];
  const float* Wl = (const float*)d_in[8];
  const float* bl = (const float*)d_in[9];
  float* out = (float*)d_out;

  const int n = in_sizes[0] / FD;      // 50000
  const int e = in_sizes[1] / 2;       // 600000
  const int* src = ei;                 // edge_index[0]
  const int* dst = ei + e;             // edge_index[1]

  // workspace carve: th (half, n*FD) | bufH (float, n*FD) | ints | sn
  __half* th  = (__half*)d_ws;                       // n*FD halves (12.8 MB)
  float* bufH = (float*)(th + (size_t)n * FD);       // n*FD floats
  int*   degi = (int*)(bufH + (size_t)n * FD);       // n
  float* dis  = (float*)(degi + n);                  // n
  int*   ptr  = (int*)(dis + n);                     // n+1
  int*   cur  = ptr + n + 1;                         // n
  int*   bsum = cur + n;                             // <=64
  int2*  sn   = (int2*)(((uintptr_t)(bsum + 64) + 15) & ~(uintptr_t)15);  // e pairs

  const int gn = (n + 255) / 256;
  const int ge = (e + 255) / 256;
  const int nb = (n + 1023) / 1024;

  k_init_deg<<<gn, 256, 0, stream>>>(degi, n);
  k_count<<<ge, 256, 0, stream>>>(dst, degi, e);
  k_dis<<<gn, 256, 0, stream>>>(degi, dis, n);
  k_scanA<<<nb, 1024, 0, stream>>>(degi, ptr, bsum, n);
  k_scanB<<<1, 64, 0, stream>>>(bsum, nb);
  k_scanC<<<gn, 256, 0, stream>>>(ptr, cur, bsum, n, e);
  k_fill<<<ge, 256, 0, stream>>>(src, dst, cur, dis, sn, e);

  dim3 gG((n + 63) / 64, 2);  // 782 row-tiles x 2 col-halves
  const int ga = n / 4;       // 12500 blocks, 4 nodes (waves) each

  k_gemm128h<<<gG, 256, 0, stream>>>(x, W1, th, n);
  k_agg<<<ga, 256, 0, stream>>>(th, ptr, sn, dis, b1, bufH, 1);
  k_gemm128h<<<gG, 256, 0, stream>>>(bufH, W2, th, n);
  k_agg<<<ga, 256, 0, stream>>>(th, ptr, sn, dis, b2, bufH, 1);
  k_gemm128h<<<gG, 256, 0, stream>>>(bufH, W3, th, n);
  k_agg_lin<<<ga, 256, 0, stream>>>(th, ptr, sn, dis, b3, Wl, bl, out);
}

// Round 9
// 325.589 us; speedup vs baseline: 1.7685x; 1.1492x over previous
//
#include <hip/hip_runtime.h>
#include <hip/hip_fp16.h>

// 3-layer GCN (PyG GCNConv semantics): deg/norm build -> CSR by dst ->
// per layer: fp16 MFMA GEMM (N x 128 @ 128 x 128, fp32 accum) then CSR
// aggregation (fp16 gather, fp32 accumulate, fp16 out) + bias (+relu),
// final 128->16 linear fused into the last aggregation (fp32 out).
//
// R9: GEMM -> mfma_f32_16x16x32_f16. A staged in LDS with XOR swizzle
// (byte ^= (row&7)<<4); W pre-packed into per-lane B-fragment order by a
// tiny conversion kernel (one packed 32KB image per layer, L2-resident).
// Agg writes fp16 directly (halves agg write + next GEMM's A read).
// Agg itself left untouched: its ~49us survived byte-halving, batching and
// request-quartering -> L3->L2 random-line fill is its wall (~1.3 TB/s on
// 64MB of 8-XCD-duplicated fetch of a 12.8MB table; random graph = no
// locality to mine).

#define FD 128
#define NCLS 16

typedef _Float16 f16x8 __attribute__((ext_vector_type(8)));
typedef float f32x4 __attribute__((ext_vector_type(4)));

__global__ __launch_bounds__(256) void k_init_deg(int* __restrict__ degi, int n) {
  int i = blockIdx.x * 256 + threadIdx.x;
  if (i < n) degi[i] = 1;  // self-loop
}

__global__ __launch_bounds__(256) void k_count(const int* __restrict__ dst,
                                               int* __restrict__ degi, int e) {
  int i = blockIdx.x * 256 + threadIdx.x;
  if (i < e) atomicAdd(&degi[dst[i]], 1);
}

__global__ __launch_bounds__(256) void k_dis(const int* __restrict__ degi,
                                             float* __restrict__ dis, int n) {
  int i = blockIdx.x * 256 + threadIdx.x;
  if (i < n) dis[i] = rsqrtf((float)degi[i]);
}

// Phase A: per-1024-chunk exclusive scan of (deg-1) = in-edge count
__global__ __launch_bounds__(1024) void k_scanA(const int* __restrict__ degi,
                                                int* __restrict__ ptr,
                                                int* __restrict__ bsum, int n) {
  __shared__ int buf[1024];
  int tid = threadIdx.x;
  int i = blockIdx.x * 1024 + tid;
  int v = (i < n) ? (degi[i] - 1) : 0;
  buf[tid] = v;
  __syncthreads();
  for (int off = 1; off < 1024; off <<= 1) {
    int t = (tid >= off) ? buf[tid - off] : 0;
    __syncthreads();
    buf[tid] += t;
    __syncthreads();
  }
  if (i < n) ptr[i] = buf[tid] - v;  // local exclusive
  if (tid == 1023) bsum[blockIdx.x] = buf[1023];
}

// Phase B: tiny serial scan of ~49 block sums
__global__ void k_scanB(int* __restrict__ bsum, int nb) {
  if (threadIdx.x == 0 && blockIdx.x == 0) {
    int run = 0;
    for (int b = 0; b < nb; ++b) { int t = bsum[b]; bsum[b] = run; run += t; }
  }
}

// Phase C: add chunk offsets, init fill cursors, write ptr[n]
__global__ __launch_bounds__(256) void k_scanC(int* __restrict__ ptr,
                                               int* __restrict__ cur,
                                               const int* __restrict__ bsum,
                                               int n, int e) {
  int i = blockIdx.x * 256 + threadIdx.x;
  if (i < n) {
    int p = ptr[i] + bsum[i >> 10];
    ptr[i] = p;
    cur[i] = p;
  }
  if (i == 0) ptr[n] = e;
}

__global__ __launch_bounds__(256) void k_fill(const int* __restrict__ src,
                                              const int* __restrict__ dst,
                                              int* __restrict__ cur,
                                              const float* __restrict__ dis,
                                              int2* __restrict__ sn, int e) {
  int i = blockIdx.x * 256 + threadIdx.x;
  if (i < e) {
    int s = src[i], d = dst[i];
    int p = atomicAdd(&cur[d], 1);
    sn[p] = make_int2(s, __float_as_int(dis[s] * dis[d]));
  }
}

// x fp32 -> fp16, 8 elements/thread. grid = n*FD/2048 (exact).
__global__ __launch_bounds__(256) void k_convx(const float* __restrict__ x,
                                               __half* __restrict__ xh) {
  int i = blockIdx.x * 256 + threadIdx.x;
  int base = i * 8;
  float4 a = *reinterpret_cast<const float4*>(&x[base]);
  float4 b = *reinterpret_cast<const float4*>(&x[base + 4]);
  __half h[8];
  h[0] = __float2half_rn(a.x); h[1] = __float2half_rn(a.y);
  h[2] = __float2half_rn(a.z); h[3] = __float2half_rn(a.w);
  h[4] = __float2half_rn(b.x); h[5] = __float2half_rn(b.y);
  h[6] = __float2half_rn(b.z); h[7] = __float2half_rn(b.w);
  *reinterpret_cast<uint4*>(&xh[base]) = *reinterpret_cast<uint4*>(h);
}

// Pack W (128x128 fp32, row-major W[k][col]) into per-lane B-fragment order:
// wp[((c*4+kc)*64 + l)*8 + j] = W[kc*32 + (l>>4)*8 + j][c*16 + (l&15)]
// so lane l's B-frag for (c,kc) is one contiguous 16B read.
// grid = 64 blocks x 256 threads = 16384 = 8c * 4kc * 64l * 8j.
__global__ __launch_bounds__(256) void k_convW(const float* __restrict__ W,
                                               __half* __restrict__ wp) {
  int i = blockIdx.x * 256 + threadIdx.x;
  int j = i & 7;
  int l = (i >> 3) & 63;
  int kc = (i >> 9) & 3;
  int c = i >> 11;
  int k = kc * 32 + ((l >> 4) << 3) + j;
  int col = c * 16 + (l & 15);
  wp[i] = __float2half_rn(W[k * FD + col]);
}

// MFMA GEMM: C[n x 128] = A[n x 128] @ W, all fp16 storage, fp32 accum.
// Block: 64 rows, 256 threads = 4 waves; wave w owns rows [w*16, w*16+16).
// A in LDS (16KB) XOR-swizzled; Wp (packed B-frags) in LDS (32KB).
// Per wave: 8 col-tiles x 4 k-chunks = 32 x mfma_f32_16x16x32_f16.
__global__ __launch_bounds__(256) void k_gemm_mfma(const __half* __restrict__ A,
                                                   const __half* __restrict__ Wp,
                                                   __half* __restrict__ C, int n) {
  __shared__ uint4 al4[1024];  // 16 KB: 64 rows x 256 B (swizzled)
  __shared__ uint4 wl4[2048];  // 32 KB: packed B-frags
  int tid = threadIdx.x;
  const uint4* wsrc = reinterpret_cast<const uint4*>(Wp);
  for (int i = tid; i < 2048; i += 256) wl4[i] = wsrc[i];

  int rbase_blk = blockIdx.x * 64;
  for (int i = tid; i < 1024; i += 256) {
    int row = i >> 4;            // 16 x 16B chunks per row
    int b = (i & 15) << 4;       // byte offset in row
    int grow = rbase_blk + row;
    if (grow > n - 1) grow = n - 1;  // clamp (tail tile): safe read
    uint4 v = *reinterpret_cast<const uint4*>(
        reinterpret_cast<const char*>(A) + (size_t)grow * 256 + b);
    *reinterpret_cast<uint4*>(
        reinterpret_cast<char*>(al4) + row * 256 + (b ^ ((row & 7) << 4))) = v;
  }
  __syncthreads();

  int l = tid & 63, wid = tid >> 6;
  int arow = wid * 16 + (l & 15);     // LDS row for A-frag (row = lane&15)
  f16x8 af[4];
#pragma unroll
  for (int kc = 0; kc < 4; ++kc) {
    int b = kc * 64 + ((l >> 4) << 4);  // k = kc*32 + 8*(l>>4), bytes
    af[kc] = *reinterpret_cast<const f16x8*>(
        reinterpret_cast<const char*>(al4) + arow * 256 + (b ^ ((arow & 7) << 4)));
  }

  int rowout = rbase_blk + wid * 16 + ((l >> 4) << 2);  // + r (0..3)
  int colb = l & 15;
  const __half* wl = reinterpret_cast<const __half*>(wl4);
#pragma unroll
  for (int c = 0; c < 8; ++c) {
    f32x4 acc = {0.f, 0.f, 0.f, 0.f};
#pragma unroll
    for (int kc = 0; kc < 4; ++kc) {
      f16x8 bf = *reinterpret_cast<const f16x8*>(&wl[((c * 4 + kc) * 64 + l) * 8]);
      acc = __builtin_amdgcn_mfma_f32_16x16x32_f16(af[kc], bf, acc, 0, 0, 0);
    }
    int col = c * 16 + colb;
#pragma unroll
    for (int r = 0; r < 4; ++r) {
      int row = rowout + r;
      if (row < n) C[(size_t)row * FD + col] = __float2half_rn(acc[r]);
    }
  }
}

// Wave-level aggregation core: lane = (h = lane>>5 edge-parity, q = lane&31
// feature group of 4). Two edges per wave VMEM instruction. Returns, in o[4],
// the full edge-sum for features q*4..q*4+3 (valid in ALL lanes after the
// xor-32 shuffle reduce).
__device__ __forceinline__ void agg_wave(const __half* __restrict__ t,
                                         const int* __restrict__ ptr,
                                         const int2* __restrict__ sn,
                                         int node, int lane, float o[4]) {
  int h = lane >> 5;
  int q = lane & 31;
  float a0 = 0.f, a1 = 0.f, a2 = 0.f, a3 = 0.f;
  int e0 = ptr[node], e1 = ptr[node + 1];
  for (int base = e0; base < e1; base += 16) {
    int s[8];
    float w[8];
#pragma unroll
    for (int j = 0; j < 8; ++j) {
      int idx = base + 2 * j + h;
      if (idx < e1) {
        int2 p = sn[idx];   // broadcast across the 32 lanes of this half
        s[j] = p.x;
        w[j] = __int_as_float(p.y);
      } else {
        s[j] = node;        // pad: hot self row, weight 0
        w[j] = 0.f;
      }
    }
    ushort4 v[8];
#pragma unroll
    for (int j = 0; j < 8; ++j)
      v[j] = *reinterpret_cast<const ushort4*>(&t[(size_t)s[j] * FD + q * 4]);
#pragma unroll
    for (int j = 0; j < 8; ++j) {
      a0 = fmaf(__half2float(__ushort_as_half(v[j].x)), w[j], a0);
      a1 = fmaf(__half2float(__ushort_as_half(v[j].y)), w[j], a1);
      a2 = fmaf(__half2float(__ushort_as_half(v[j].z)), w[j], a2);
      a3 = fmaf(__half2float(__ushort_as_half(v[j].w)), w[j], a3);
    }
  }
  // combine the two edge-parity halves: every lane ends with the full sum
  o[0] = a0 + __shfl(a0, lane ^ 32, 64);
  o[1] = a1 + __shfl(a1, lane ^ 32, 64);
  o[2] = a2 + __shfl(a2, lane ^ 32, 64);
  o[3] = a3 + __shfl(a3, lane ^ 32, 64);
}

// 4 nodes per 256-thread block (1 wave per node): agg + bias (+relu), fp16 out.
__global__ __launch_bounds__(256) void k_agg(const __half* __restrict__ t,
                                             const int* __restrict__ ptr,
                                             const int2* __restrict__ sn,
                                             const float* __restrict__ dis,
                                             const float* __restrict__ bias,
                                             __half* __restrict__ out, int relu) {
  int lane = threadIdx.x & 63;
  int node = blockIdx.x * 4 + (threadIdx.x >> 6);
  float d = dis[node];
  float dd = d * d;
  float o[4];
  agg_wave(t, ptr, sn, node, lane, o);
  if (lane < 32) {
    int q = lane;
    ushort4 sv = *reinterpret_cast<const ushort4*>(&t[(size_t)node * FD + q * 4]);
    float4 b = *reinterpret_cast<const float4*>(&bias[q * 4]);
    o[0] = fmaf(__half2float(__ushort_as_half(sv.x)), dd, o[0]) + b.x;
    o[1] = fmaf(__half2float(__ushort_as_half(sv.y)), dd, o[1]) + b.y;
    o[2] = fmaf(__half2float(__ushort_as_half(sv.z)), dd, o[2]) + b.z;
    o[3] = fmaf(__half2float(__ushort_as_half(sv.w)), dd, o[3]) + b.w;
    if (relu) {
      o[0] = fmaxf(o[0], 0.f);
      o[1] = fmaxf(o[1], 0.f);
      o[2] = fmaxf(o[2], 0.f);
      o[3] = fmaxf(o[3], 0.f);
    }
    __half hh[4];
    hh[0] = __float2half_rn(o[0]);
    hh[1] = __float2half_rn(o[1]);
    hh[2] = __float2half_rn(o[2]);
    hh[3] = __float2half_rn(o[3]);
    *reinterpret_cast<uint2*>(&out[(size_t)node * FD + q * 4]) =
        *reinterpret_cast<uint2*>(hh);
  }
}

// Last layer: agg + b3 into LDS, then fused h @ Wlin + blin -> out[node][16].
__global__ __launch_bounds__(256) void k_agg_lin(const __half* __restrict__ t,
                                                 const int* __restrict__ ptr,
                                                 const int2* __restrict__ sn,
                                                 const float* __restrict__ dis,
                                                 const float* __restrict__ b3,
                                                 const float* __restrict__ Wl,
                                                 const float* __restrict__ bl,
                                                 float* __restrict__ out) {
  __shared__ float hl[4][FD];
  int wid = threadIdx.x >> 6;
  int lane = threadIdx.x & 63;
  int node = blockIdx.x * 4 + wid;
  float d = dis[node];
  float dd = d * d;
  float o[4];
  agg_wave(t, ptr, sn, node, lane, o);
  if (lane < 32) {
    int q = lane;
    ushort4 sv = *reinterpret_cast<const ushort4*>(&t[(size_t)node * FD + q * 4]);
    float4 b = *reinterpret_cast<const float4*>(&b3[q * 4]);
    hl[wid][q * 4 + 0] = fmaf(__half2float(__ushort_as_half(sv.x)), dd, o[0]) + b.x;
    hl[wid][q * 4 + 1] = fmaf(__half2float(__ushort_as_half(sv.y)), dd, o[1]) + b.y;
    hl[wid][q * 4 + 2] = fmaf(__half2float(__ushort_as_half(sv.z)), dd, o[2]) + b.z;
    hl[wid][q * 4 + 3] = fmaf(__half2float(__ushort_as_half(sv.w)), dd, o[3]) + b.w;
  }
  __syncthreads();
  // 64 lanes: c = lane&15 (class), kc = lane>>4 (k-chunk of 32)
  int c = lane & 15, kc = lane >> 4;
  float s = 0.f;
#pragma unroll
  for (int k0 = 0; k0 < 32; ++k0) {
    int k = kc * 32 + k0;
    s = fmaf(hl[wid][k], Wl[k * NCLS + c], s);
  }
  s += __shfl(s, lane ^ 16, 64);
  s += __shfl(s, lane ^ 32, 64);
  if (lane < NCLS)
    out[(size_t)node * NCLS + lane] = s + bl[lane];
}

extern "C" void kernel_launch(void* const* d_in, const int* in_sizes, int n_in,
                              void* d_out, int out_size, void* d_ws, size_t ws_size,
                              hipStream_t stream) {
  const float* x  = (const float*)d_in[0];
  const int*   ei = (const int*)d_in[1];
  const float* W1 = (const float*)d_in[2];
  const float* b1 = (const float*)d_in[3];
  const float* W2 = (const float*)d_in[4];
  const float* b2 = (const float*)d_in[5];
  const float* W3 = (const float*)d_in[6];
  const float* b3 = (const float*)d_in[7];
  const float* Wl = (const float*)d_in[8];
  const float* bl = (const float*)d_in[9];
  float* out = (float*)d_out;

  const int n = in_sizes[0] / FD;      // 50000
  const int e = in_sizes[1] / 2;       // 600000
  const int* src = ei;                 // edge_index[0]
  const int* dst = ei + e;             // edge_index[1]

  // workspace carve: thA | thB | xh (half, n*FD each) | wp1..3 | ints | sn
  __half* thA = (__half*)d_ws;                        // n*FD halves
  __half* thB = thA + (size_t)n * FD;                 // n*FD halves
  __half* xh  = thB + (size_t)n * FD;                 // n*FD halves
  __half* wp1 = xh + (size_t)n * FD;                  // 16384
  __half* wp2 = wp1 + 16384;                          // 16384
  __half* wp3 = wp2 + 16384;                          // 16384
  int*   degi = (int*)(wp3 + 16384);                  // n
  float* dis  = (float*)(degi + n);                   // n
  int*   ptr  = (int*)(dis + n);                      // n+1
  int*   cur  = ptr + n + 1;                          // n
  int*   bsum = cur + n;                              // <=64
  int2*  sn   = (int2*)(((uintptr_t)(bsum + 64) + 15) & ~(uintptr_t)15);  // e pairs

  const int gn = (n + 255) / 256;
  const int ge = (e + 255) / 256;
  const int nb = (n + 1023) / 1024;

  k_init_deg<<<gn, 256, 0, stream>>>(degi, n);
  k_count<<<ge, 256, 0, stream>>>(dst, degi, e);
  k_dis<<<gn, 256, 0, stream>>>(degi, dis, n);
  k_scanA<<<nb, 1024, 0, stream>>>(degi, ptr, bsum, n);
  k_scanB<<<1, 64, 0, stream>>>(bsum, nb);
  k_scanC<<<gn, 256, 0, stream>>>(ptr, cur, bsum, n, e);
  k_fill<<<ge, 256, 0, stream>>>(src, dst, cur, dis, sn, e);

  k_convx<<<(n * FD) / 2048, 256, 0, stream>>>(x, xh);
  k_convW<<<64, 256, 0, stream>>>(W1, wp1);
  k_convW<<<64, 256, 0, stream>>>(W2, wp2);
  k_convW<<<64, 256, 0, stream>>>(W3, wp3);

  const int gG = (n + 63) / 64;  // 782 row-tiles
  const int ga = n / 4;          // 12500 blocks, 4 nodes (waves) each

  k_gemm_mfma<<<gG, 256, 0, stream>>>(xh, wp1, thA, n);
  k_agg<<<ga, 256, 0, stream>>>(thA, ptr, sn, dis, b1, thB, 1);
  k_gemm_mfma<<<gG, 256, 0, stream>>>(thB, wp2, thA, n);
  k_agg<<<ga, 256, 0, stream>>>(thA, ptr, sn, dis, b2, thB, 1);
  k_gemm_mfma<<<gG, 256, 0, stream>>>(thB, wp3, thA, n);
  k_agg_lin<<<ga, 256, 0, stream>>>(thA, ptr, sn, dis, b3, Wl, bl, out);
}